// Round 8
// baseline (104.132 us; speedup 1.0000x reference)
//
#include <hip/hip_runtime.h>
#include <cstddef>

#define T_N 2048
#define M_N 4096   // B*T
#define KW  512    // GEMM K

typedef __attribute__((ext_vector_type(4))) float f32x4;
typedef _Float16 f16x8 __attribute__((ext_vector_type(8)));
typedef _Float16 f16x4 __attribute__((ext_vector_type(4)));
typedef _Float16 f16x2 __attribute__((ext_vector_type(2)));

#define GLOAD_LDS(g, l) __builtin_amdgcn_global_load_lds( \
    (const __attribute__((address_space(1))) unsigned int*)(g), \
    (__attribute__((address_space(3))) unsigned int*)(l), 16, 0, 0)

// ---------------- prep: x->f16, W's packed/permuted f16, trig f16x2 -------
// blocks [0,1024): x pack; [1024,1280): W packs; [1280,3328): trig table
__global__ __launch_bounds__(256) void prep(
    const float* __restrict__ x, const float* __restrict__ Wq,
    const float* __restrict__ Wkv, const float* __restrict__ Wlin,
    _Float16* __restrict__ Axp, _Float16* __restrict__ Wcatp,
    _Float16* __restrict__ Wlinp, _Float16* __restrict__ tab16) {
  __shared__ float tile[64][65];
  const int bid = blockIdx.x;
  const int tid = threadIdx.x;
  if (bid < 1024) {
    int idx = bid * 256 + tid;           // M*64 ids
    int m = idx >> 6, k8 = (idx & 63) << 3;
    const float* src = x + (size_t)m * 512 + k8;
    const float4 a = *(const float4*)src;
    const float4 b = *(const float4*)(src + 4);
    f16x8 o;
    o[0] = (_Float16)a.x; o[1] = (_Float16)a.y; o[2] = (_Float16)a.z; o[3] = (_Float16)a.w;
    o[4] = (_Float16)b.x; o[5] = (_Float16)b.y; o[6] = (_Float16)b.z; o[7] = (_Float16)b.w;
    *(f16x8*)(Axp + (size_t)m * 512 + k8) = o;
    return;
  }
  if (bid >= 1280) {
    int gid = (bid - 1280) * 256 + tid;  // T*256 ids
    int t = gid >> 8, f = gid & 255;
    float invf = exp2f(-0.05190512648261503f * (float)f);  // 10000^(-f/256)
    float s, c;
    sincosf((float)t * invf, &s, &c);
    f16x2 cs;
    cs[0] = (_Float16)c; cs[1] = (_Float16)s;
    *(f16x2*)(tab16 + 2 * ((size_t)t * 256 + f)) = cs;
    return;
  }
  int wb = bid - 1024;
  const float* W; int N; int mode; int bx, by;
  if (wb < 64)       { W = Wq;   N = 512;  mode = 0; bx = wb & 7;  by = wb >> 3; }
  else if (wb < 192) { wb -= 64;  W = Wkv; N = 1024; mode = 1; bx = wb & 15; by = wb >> 4; }
  else               { wb -= 192; W = Wlin; N = 512; mode = 2; bx = wb & 7;  by = wb >> 3; }
  const int n0 = bx * 64, k0 = by * 64;
#pragma unroll
  for (int it = 0; it < 16; ++it) {
    int idx = tid + it * 256;
    int r = idx >> 6, c = idx & 63;
    tile[r][c] = W[(size_t)(k0 + r) * N + n0 + c];
  }
  __syncthreads();
#pragma unroll
  for (int it = 0; it < 16; ++it) {
    int idx = tid + it * 256;
    int n = idx >> 6, kk = idx & 63;
    int cg = n0 + n;
    int np; _Float16* out;
    if (mode == 0)      { np = 2 * (cg & 255) + (cg >> 8); out = Wcatp; }
    else if (mode == 1) { np = (cg < 512) ? 512 + 2 * (cg & 255) + (cg >> 8)
                                          : 1024 + (cg - 512);
                          out = Wcatp; }
    else                { np = cg; out = Wlinp; }
    out[(size_t)np * KW + k0 + kk] = (_Float16)tile[kk][n];
  }
}

// ---------------- qkv GEMM + fused RoPE + coalesced LDS epilogue ----------
__global__ __launch_bounds__(256) void gemm_qkv_rope(
    const _Float16* __restrict__ Ap, const _Float16* __restrict__ Bp,
    const _Float16* __restrict__ tab16, _Float16* __restrict__ Qh,
    _Float16* __restrict__ Kh, _Float16* __restrict__ Vh) {
  __shared__ __align__(16) _Float16 sm[64 * 64 + 128 * 64];  // 12288 f16
  _Float16* sA = sm;
  _Float16* sB = sm + 64 * 64;
  const int tid = threadIdx.x;
  const int wid = tid >> 6, lane = tid & 63;
  const int il = lane & 15, g = lane >> 4;
  const int m0 = blockIdx.y * 64, n0 = blockIdx.x * 128;
  const int wm = (wid >> 1) * 32, wn = (wid & 1) * 64;
  f32x4 acc[2][4] = {};

  const _Float16* ga = Ap + (size_t)(m0 + wid * 16 + (lane >> 3)) * KW + (lane & 7) * 8;
  const _Float16* gb = Bp + (size_t)(n0 + wid * 32 + (lane >> 3)) * KW + (lane & 7) * 8;
  _Float16* la = sA + wid * 16 * 64;
  _Float16* lb = sB + wid * 32 * 64;

  for (int k0 = 0; k0 < KW; k0 += 64) {
    GLOAD_LDS(ga + k0, la);
    GLOAD_LDS(ga + 8 * KW + k0, la + 8 * 64);
#pragma unroll
    for (int p = 0; p < 4; ++p)
      GLOAD_LDS(gb + (size_t)(p * 8) * KW + k0, lb + p * 8 * 64);
    __syncthreads();
#pragma unroll
    for (int ks = 0; ks < 2; ++ks) {
      f16x8 af[2], bf[4];
#pragma unroll
      for (int i = 0; i < 2; ++i)
        af[i] = *(const f16x8*)&sA[(wm + i * 16 + il) * 64 + ks * 32 + g * 8];
#pragma unroll
      for (int j = 0; j < 4; ++j)
        bf[j] = *(const f16x8*)&sB[(wn + j * 16 + il) * 64 + ks * 32 + g * 8];
#pragma unroll
      for (int i = 0; i < 2; ++i)
#pragma unroll
        for (int j = 0; j < 4; ++j)
          acc[i][j] = __builtin_amdgcn_mfma_f32_16x16x32_f16(af[i], bf[j], acc[i][j], 0, 0, 0);
    }
    __syncthreads();
  }
  // ---- epilogue (C/D layout: col=il on N side, row=g*4+r on M side)
  const int b8 = (m0 >> 11) * 8;
  const int tb = m0 & (T_N - 1);
  const bool isv = (n0 >= 1024);
  const bool isk = (n0 >= 512) && !isv;
  _Float16* OT  = sm;                    // [2][64][72] for q/k
  _Float16* OTV = sm;                    // [128][72]  for v

  if (isv) {
#pragma unroll
    for (int i = 0; i < 2; ++i)
#pragma unroll
      for (int j = 0; j < 4; ++j) {
        f32x4 v = acc[i][j];
        int col = wn + 16 * j + il;
#pragma unroll
        for (int r = 0; r < 4; ++r) {
          int tl = wm + i * 16 + g * 4 + r;
          OTV[col * 72 + tl] = (_Float16)v[r];
        }
      }
    __syncthreads();
    const int cv = n0 - 1024;
#pragma unroll
    for (int it = 0; it < 4; ++it) {
      int c = tid + it * 256;             // 1024 chunks
      int col = c >> 3, t8 = (c & 7) * 8;
      int h = (cv + col) >> 6, d = (cv + col) & 63;
      *(f16x8*)(Vh + ((size_t)(b8 + h) * 64 + d) * T_N + tb + t8) =
          *(const f16x8*)&OTV[col * 72 + t8];
    }
    return;
  }
  const int n0p = n0 - (isk ? 512 : 0);
  const int h0 = n0p >> 7;                // head index base
#pragma unroll
  for (int i = 0; i < 2; ++i) {
#pragma unroll
    for (int j = 0; j < 4; ++j) {
      f32x4 v = acc[i][j];
#pragma unroll
      for (int r = 0; r < 4; ++r) {
        float self = v[r];
        float part = __shfl_xor(self, 1);
        int tl = wm + i * 16 + g * 4 + r;
        int tpos = tb + tl;
        int p = il & 1;
        int f = (n0p + wn + 16 * j + (il & 14)) >> 1;
        f16x2 cs = *(const f16x2*)(tab16 + 2 * ((size_t)tpos * 256 + f));
        float c = (float)cs[0], s = (float)cs[1];
        float o = p ? (self * c + part * s) : (self * c - part * s);
        OT[(p * 64 + tl) * 72 + (f & 63)] = (_Float16)o;
      }
    }
  }
  __syncthreads();
  _Float16* dst = isk ? Kh : Qh;
#pragma unroll
  for (int it = 0; it < 4; ++it) {
    int c = tid + it * 256;               // 1024 chunks: 2 planes x 64 t x 8
    int p = c >> 9, row = (c >> 3) & 63, d8 = (c & 7) * 8;
    *(f16x8*)(dst + ((size_t)(b8 + h0 + 4 * p) * T_N + tb + row) * 64 + d8) =
        *(const f16x8*)&OT[(p * 64 + row) * 72 + d8];
  }
}

// ---------------- fused attention, AT=64: wave-owned rows -----------------
// 512 blocks = one (b,h,64-row tile) each; 4 waves, wave it owns rows
// [16it,16it+16). j-band per wave: tiles it..it+4 (+1 zeroed for PV align).
// LDS f16: Ks[128][72]@0 | VTs[64][136]@9216 | Qs[64][72]@17920 |
//          Ps[64][136]@22528 ; OH[64][72] overlays Ks after barrier.
__global__ __launch_bounds__(256, 2) void attn_fused(
    const _Float16* __restrict__ Qh, const _Float16* __restrict__ Kh,
    const _Float16* __restrict__ Vh, _Float16* __restrict__ Aout) {
  __shared__ __align__(16) _Float16 sm[31232];   // 62464 B
  _Float16* Ks  = sm;
  _Float16* VTs = sm + 9216;
  _Float16* Qs  = sm + 17920;
  _Float16* Ps  = sm + 22528;
  _Float16* OH  = sm;           // epilogue overlay

  const int wgid = blockIdx.x;
  const int orig = (wgid & 7) * 64 + (wgid >> 3);   // XCD swizzle (512 = 8*64)
  const int tile = orig & 31;
  const int h = (orig >> 5) & 7;
  const int b = orig >> 8;
  const int t0 = tile * 64;
  const int tid = threadIdx.x;
  const size_t bh = (size_t)(b * 8 + h);

  // ---- stage Q (64x64)
#pragma unroll
  for (int itn = 0; itn < 2; ++itn) {
    int c = tid + itn * 256;
    int row = c >> 3, d8 = (c & 7) * 8;
    *(f16x8*)(Qs + row * 72 + d8) =
        *(const f16x8*)(Qh + (bh * T_N + t0 + row) * 64 + d8);
  }
  // ---- stage K (128x64), p = t0-64+jr, zero for p<0
#pragma unroll
  for (int itn = 0; itn < 4; ++itn) {
    int c = tid + itn * 256;
    int jr = c >> 3, d8 = (c & 7) * 8;
    int p = t0 - 64 + jr;
    f16x8 o = {};
    if (p >= 0) o = *(const f16x8*)(Kh + (bh * T_N + p) * 64 + d8);
    *(f16x8*)(Ks + jr * 72 + d8) = o;
  }
  // ---- stage VT (64 d x 128 j) from transposed Vh
#pragma unroll
  for (int itn = 0; itn < 4; ++itn) {
    int c = tid + itn * 256;
    int d = c & 63, jr8 = (c >> 6) * 8;
    int p8 = t0 - 64 + jr8;
    f16x8 o = {};
    if (p8 >= 0) o = *(const f16x8*)(Vh + (bh * 64 + d) * T_N + p8);
    *(f16x8*)(VTs + d * 136 + jr8) = o;
  }
  __syncthreads();

  // ---- wave roles: wave it owns q-rows [16it, 16it+16)
  const int lane = tid & 63;
  const int il = lane & 15, g = lane >> 4;
  const int it = tid >> 6;
  const int i_q = 16 * it + il;

  // QK^T (swapped): sacc[jt5][r] = S^T[j][i_q], j = 16*(it+jt5)+4g+r
  f32x4 sacc[5] = {};
  {
    f16x8 qf0 = *(const f16x8*)(Qs + i_q * 72 + 8 * g);
    f16x8 qf1 = *(const f16x8*)(Qs + i_q * 72 + 32 + 8 * g);
#pragma unroll
    for (int jt5 = 0; jt5 < 5; ++jt5) {
      int jrow = 16 * (it + jt5) + il;
      f16x8 a0 = *(const f16x8*)(Ks + jrow * 72 + 8 * g);
      f16x8 a1 = *(const f16x8*)(Ks + jrow * 72 + 32 + 8 * g);
      sacc[jt5] = __builtin_amdgcn_mfma_f32_16x16x32_f16(a0, qf0, sacc[jt5], 0, 0, 0);
      sacc[jt5] = __builtin_amdgcn_mfma_f32_16x16x32_f16(a1, qf1, sacc[jt5], 0, 0, 0);
    }
  }
  // ---- softmax: rows wave-local; reduce across g via shfl only
  float mx = -3e38f;
#pragma unroll
  for (int jt5 = 0; jt5 < 5; ++jt5)
#pragma unroll
    for (int r = 0; r < 4; ++r) {
      int j = 16 * (it + jt5) + 4 * g + r;
      int wv = j - 1 - i_q;
      if (wv >= 0 && wv < 64) mx = fmaxf(mx, sacc[jt5][r]);
    }
  mx = fmaxf(mx, __shfl_xor(mx, 16));
  mx = fmaxf(mx, __shfl_xor(mx, 32));
  float sum = 0.f;
#pragma unroll
  for (int jt5 = 0; jt5 < 5; ++jt5) {
    f16x4 pv;
#pragma unroll
    for (int r = 0; r < 4; ++r) {
      int j = 16 * (it + jt5) + 4 * g + r;
      int wv = j - 1 - i_q;
      float ex = 0.f;
      if (wv >= 0 && wv < 64) {
        ex = exp2f((sacc[jt5][r] - mx) * 0.18033688011112042f);  // *0.125*log2(e)
        sum += ex;
      }
      pv[r] = (_Float16)ex;
    }
    *(f16x4*)(Ps + i_q * 136 + 16 * (it + jt5) + 4 * g) = pv;
  }
  sum += __shfl_xor(sum, 16);
  sum += __shfl_xor(sum, 32);
  {  // zero the extra tile PV's 32-aligned chunks touch
    int jtz = (it & 1) ? (it - 1) : (it + 5);
    f16x4 z = {};
    *(f16x4*)(Ps + i_q * 136 + 16 * jtz + 4 * g) = z;
  }

  // ---- PV: out[i][d] = sum_j P[i][j] * VT[d][j]; all P rows wave-local
  const int jb = 32 * (it >> 1);
  f32x4 oacc[4] = {};
#pragma unroll
  for (int ks = 0; ks < 3; ++ks) {
    f16x8 pf = *(const f16x8*)(Ps + i_q * 136 + jb + 32 * ks + 8 * g);
#pragma unroll
    for (int dt = 0; dt < 4; ++dt) {
      f16x8 vf = *(const f16x8*)(VTs + (16 * dt + il) * 136 + jb + 32 * ks + 8 * g);
      oacc[dt] = __builtin_amdgcn_mfma_f32_16x16x32_f16(pf, vf, oacc[dt], 0, 0, 0);
    }
  }
  __syncthreads();   // all Ks reads done before OH overlay
  // ---- epilogue: normalize (sum via shfl), stage OH, coalesced write
#pragma unroll
  for (int r = 0; r < 4; ++r) {
    float s4 = __shfl(sum, 4 * g + r);
    float inv = 1.f / s4;
    int i = 16 * it + 4 * g + r;
#pragma unroll
    for (int dt = 0; dt < 4; ++dt) {
      int d = 16 * dt + il;
      OH[i * 72 + d] = (_Float16)(oacc[dt][r] * inv);
    }
  }
  __syncthreads();
#pragma unroll
  for (int itn = 0; itn < 2; ++itn) {
    int c = tid + itn * 256;
    int row = c >> 3, d8 = (c & 7) * 8;
    *(f16x8*)(Aout + ((size_t)(b * T_N + t0 + row)) * 512 + h * 64 + d8) =
        *(const f16x8*)(OH + row * 72 + d8);
  }
}

// ---------------- output GEMM: out = Aaop @ Wlinp^T + blin ----------------
__global__ __launch_bounds__(256) void gemm_out(
    const _Float16* __restrict__ Ap, const _Float16* __restrict__ Bp,
    const float* __restrict__ bias, float* __restrict__ C) {
  __shared__ __align__(16) _Float16 sA[64 * 64];
  __shared__ __align__(16) _Float16 sB[64 * 64];
  const int tid = threadIdx.x;
  const int wid = tid >> 6, lane = tid & 63;
  const int il = lane & 15, g = lane >> 4;
  const int m0 = blockIdx.y * 64, n0 = blockIdx.x * 64;
  const int wm = (wid >> 1) * 32, wn = (wid & 1) * 32;
  f32x4 acc[2][2] = {};

  const _Float16* ga = Ap + (size_t)(m0 + wid * 16 + (lane >> 3)) * KW + (lane & 7) * 8;
  const _Float16* gb = Bp + (size_t)(n0 + wid * 16 + (lane >> 3)) * KW + (lane & 7) * 8;
  _Float16* la = sA + wid * 16 * 64;
  _Float16* lb = sB + wid * 16 * 64;

  for (int k0 = 0; k0 < KW; k0 += 64) {
    GLOAD_LDS(ga + k0, la);
    GLOAD_LDS(ga + 8 * KW + k0, la + 8 * 64);
    GLOAD_LDS(gb + k0, lb);
    GLOAD_LDS(gb + 8 * KW + k0, lb + 8 * 64);
    __syncthreads();
#pragma unroll
    for (int ks = 0; ks < 2; ++ks) {
      f16x8 af[2], bf[2];
#pragma unroll
      for (int i = 0; i < 2; ++i)
        af[i] = *(const f16x8*)&sA[(wm + i * 16 + il) * 64 + ks * 32 + g * 8];
#pragma unroll
      for (int j = 0; j < 2; ++j)
        bf[j] = *(const f16x8*)&sB[(wn + j * 16 + il) * 64 + ks * 32 + g * 8];
#pragma unroll
      for (int i = 0; i < 2; ++i)
#pragma unroll
        for (int j = 0; j < 2; ++j)
          acc[i][j] = __builtin_amdgcn_mfma_f32_16x16x32_f16(af[i], bf[j], acc[i][j], 0, 0, 0);
    }
    __syncthreads();
  }
  const int cn = n0 + wn + il;
  const int rbase = m0 + wm + g * 4;
#pragma unroll
  for (int j = 0; j < 2; ++j) {
    float badd = bias[cn + j * 16];
#pragma unroll
    for (int i = 0; i < 2; ++i)
#pragma unroll
      for (int r = 0; r < 4; ++r)
        C[(size_t)(rbase + i * 16 + r) * 512 + cn + j * 16] = acc[i][j][r] + badd;
  }
}

// ---------------- launch ---------------------------------------------------
extern "C" void kernel_launch(void* const* d_in, const int* in_sizes, int n_in,
                              void* d_out, int out_size, void* d_ws, size_t ws_size,
                              hipStream_t stream) {
  const float* x    = (const float*)d_in[0];
  const float* Wq   = (const float*)d_in[1];
  const float* Wkv  = (const float*)d_in[2];
  const float* Wlin = (const float*)d_in[3];
  const float* blin = (const float*)d_in[4];
  float* out = (float*)d_out;

  char* ws = (char*)d_ws;
  _Float16* Axp   = (_Float16*)(ws);              // 4194304
  _Float16* Wcatp = (_Float16*)(ws + 4194304);    // 1572864
  _Float16* Wlinp = (_Float16*)(ws + 5767168);    //  524288
  _Float16* tab16 = (_Float16*)(ws + 6291456);    // 2097152
  _Float16* Qh    = (_Float16*)(ws + 8388608);    // 4194304
  _Float16* Kh    = (_Float16*)(ws + 12582912);   // 4194304
  _Float16* Vh    = (_Float16*)(ws + 16777216);   // 4194304
  _Float16* Aaop  = (_Float16*)(ws + 20971520);   // 4194304 (end 25165824)

  prep<<<3328, 256, 0, stream>>>(x, Wq, Wkv, Wlin, Axp, Wcatp, Wlinp, tab16);
  gemm_qkv_rope<<<dim3(12, 64), 256, 0, stream>>>(Axp, Wcatp, tab16, Qh, Kh, Vh);
  attn_fused<<<512, 256, 0, stream>>>(Qh, Kh, Vh, Aaop);
  gemm_out<<<dim3(8, 64), 256, 0, stream>>>(Aaop, Wlinp, blin, out);
}